// Round 1
// baseline (259.388 us; speedup 1.0000x reference)
//
#include <hip/hip_runtime.h>
#include <cstdint>
#include <cstddef>

#define BB 2
#define CC 256
#define NN 16
#define LL 4096
#define NCH 128
#define CLEN 32

__device__ __forceinline__ void dir_params(int d, int& start, int& outer, int& inner) {
    if (d == 0)      { start = 0;    outer =  64; inner =  1; }
    else if (d == 1) { start = 4095; outer = -64; inner = -1; }
    else if (d == 2) { start = 4032; outer = -64; inner =  1; }
    else             { start = 63;   outer =  -1; inner = 64; }
}

__device__ __forceinline__ float softplus_f(float z) {
    return fmaxf(z, 0.f) + log1pf(expf(-fabsf(z)));
}

// ---------------- K1: delta = softplus(X @ W_delta + b), u = delta * x -------
// X[l,k] = feat[b,k,l]; out (B,L,C) layouts for delta,u (c contiguous).
__global__ __launch_bounds__(256) void k1_delta_gemm(
    const float* __restrict__ feat, const float* __restrict__ Wd,
    const float* __restrict__ bd, float* __restrict__ delta, float* __restrict__ u)
{
    int ctile = blockIdx.x & 3;
    int lt    = (blockIdx.x >> 2) & 63;
    int b     = blockIdx.x >> 8;
    int l0 = lt * 64, c0 = ctile * 64;
    __shared__ float As[16][64];
    __shared__ float Bs[16][64];
    int tx = threadIdx.x & 15, ty = threadIdx.x >> 4;
    int arow = ty;
    int acol = tx * 4;
    float acc[4][4] = {};
    const float* fbase = feat + (size_t)b * CC * LL;
    for (int k0 = 0; k0 < 256; k0 += 16) {
        __syncthreads();
        *(float4*)&As[arow][acol] = *(const float4*)&fbase[(size_t)(k0 + arow) * LL + l0 + acol];
        *(float4*)&Bs[arow][acol] = *(const float4*)&Wd[(size_t)(k0 + arow) * CC + c0 + acol];
        __syncthreads();
        #pragma unroll
        for (int kk = 0; kk < 16; ++kk) {
            float4 a = *(float4*)&As[kk][ty * 4];
            float4 w = *(float4*)&Bs[kk][tx * 4];
            float av[4] = {a.x, a.y, a.z, a.w};
            float wv[4] = {w.x, w.y, w.z, w.w};
            #pragma unroll
            for (int i = 0; i < 4; ++i)
                #pragma unroll
                for (int j = 0; j < 4; ++j)
                    acc[i][j] = fmaf(av[i], wv[j], acc[i][j]);
        }
    }
    float bdv[4];
    #pragma unroll
    for (int j = 0; j < 4; ++j) bdv[j] = bd[c0 + tx * 4 + j];
    float4 fcol[4];
    #pragma unroll
    for (int j = 0; j < 4; ++j)
        fcol[j] = *(const float4*)&fbase[(size_t)(c0 + tx * 4 + j) * LL + l0 + ty * 4];
    float fc[4][4];
    fc[0][0]=fcol[0].x; fc[0][1]=fcol[1].x; fc[0][2]=fcol[2].x; fc[0][3]=fcol[3].x;
    fc[1][0]=fcol[0].y; fc[1][1]=fcol[1].y; fc[1][2]=fcol[2].y; fc[1][3]=fcol[3].y;
    fc[2][0]=fcol[0].z; fc[2][1]=fcol[1].z; fc[2][2]=fcol[2].z; fc[2][3]=fcol[3].z;
    fc[3][0]=fcol[0].w; fc[3][1]=fcol[1].w; fc[3][2]=fcol[2].w; fc[3][3]=fcol[3].w;
    #pragma unroll
    for (int i = 0; i < 4; ++i) {
        int l = l0 + ty * 4 + i;
        float dv[4], uv[4];
        #pragma unroll
        for (int j = 0; j < 4; ++j) {
            float z = acc[i][j] + bdv[j];
            dv[j] = softplus_f(z);
            uv[j] = dv[j] * fc[i][j];
        }
        size_t o = ((size_t)b * LL + l) * CC + c0 + tx * 4;
        *(float4*)&delta[o] = make_float4(dv[0], dv[1], dv[2], dv[3]);
        *(float4*)&u[o]     = make_float4(uv[0], uv[1], uv[2], uv[3]);
    }
}

// ---------------- K2: Bm = X @ W_B, Cm = X @ W_C  (B,L,N) -------------------
__global__ __launch_bounds__(256) void k2_bc_gemm(
    const float* __restrict__ feat, const float* __restrict__ WB,
    const float* __restrict__ WC, float* __restrict__ Bm, float* __restrict__ Cm)
{
    int lt = blockIdx.x & 63;
    int b  = blockIdx.x >> 6;
    int l  = lt * 64 + (threadIdx.x & 63);
    int unit = threadIdx.x >> 6;   // wave-uniform
    __shared__ float sW[8192];
    for (int i = threadIdx.x; i < 4096; i += 256) {
        sW[i]        = WB[i];
        sW[4096 + i] = WC[i];
    }
    __syncthreads();
    int mat = unit >> 1;
    int nb  = (unit & 1) * 8;
    const float* wbase = &sW[mat * 4096 + nb];
    float acc[8] = {};
    const float* fcol = feat + (size_t)b * CC * LL + l;
    #pragma unroll 4
    for (int k = 0; k < 256; ++k) {
        float xv = fcol[(size_t)k * LL];
        #pragma unroll
        for (int j = 0; j < 8; ++j)
            acc[j] = fmaf(xv, wbase[k * 16 + j], acc[j]);
    }
    float* dst = (mat ? Cm : Bm) + ((size_t)b * LL + l) * NN + nb;
    *(float4*)&dst[0] = make_float4(acc[0], acc[1], acc[2], acc[3]);
    *(float4*)&dst[4] = make_float4(acc[4], acc[5], acc[6], acc[7]);
}

// ---------------- K3: phase 1 — per-chunk aggregates (P, S) -----------------
// block = (d, b, ch); thread = c; each thread carries all 16 n in registers.
__global__ __launch_bounds__(256) void k3_phase1(
    const float* __restrict__ delta, const float* __restrict__ u,
    const float* __restrict__ Bm, const float* __restrict__ A_log,
    float* __restrict__ P, float* __restrict__ S)
{
    int blk = blockIdx.x;
    int ch = blk & 127;
    int db = blk >> 7;
    int b = db & 1, d = db >> 1;
    int c = threadIdx.x;
    int start, outer, inner;
    dir_params(d, start, outer, inner);
    int oi = ch >> 1;
    int ibase = (ch & 1) * 32;
    int p0 = start + outer * oi + inner * ibase;
    __shared__ float sBm[CLEN * NN];
    for (int i = threadIdx.x; i < CLEN * NN; i += 256) {
        int j = i >> 4, n = i & 15;
        int p = p0 + inner * j;
        sBm[i] = Bm[((size_t)b * LL + p) * NN + n];
    }
    float A2[NN];
    #pragma unroll
    for (int n = 0; n < NN; ++n)
        A2[n] = -expf(A_log[c * NN + n]) * 1.4426950408889634f;
    __syncthreads();
    float Sv[NN] = {};
    float sumd = 0.f;
    const float* dbase = delta + (size_t)b * LL * CC + c;
    const float* ubase = u     + (size_t)b * LL * CC + c;
    for (int j = 0; j < CLEN; ++j) {
        int p = p0 + inner * j;
        float dl = dbase[(size_t)p * CC];
        float uv = ubase[(size_t)p * CC];
        sumd += dl;
        #pragma unroll
        for (int n = 0; n < NN; ++n) {
            float dA = exp2f(A2[n] * dl);
            Sv[n] = fmaf(dA, Sv[n], uv * sBm[j * 16 + n]);
        }
    }
    size_t base = (size_t)blk * 4096 + (size_t)c * 16;
    #pragma unroll
    for (int n = 0; n < NN; ++n) {
        P[base + n] = exp2f(A2[n] * sumd);   // exp of sum == product of exps
        S[base + n] = Sv[n];
    }
}

// ---------------- K4: phase 2 — scan over chunk aggregates (in-place Hin) ---
__global__ __launch_bounds__(256) void k4_phase2(
    const float* __restrict__ P, float* __restrict__ S)
{
    int g = blockIdx.x * 256 + threadIdx.x;     // 32768 = (d*2+b) * 4096 + c*16+n
    int cn = g & 4095;
    int db = g >> 12;
    size_t base = (size_t)db * NCH * 4096 + cn;
    float h = 0.f;
    for (int ch = 0; ch < NCH; ++ch) {
        size_t idx = base + (size_t)ch * 4096;
        float pp = P[idx];
        float ss = S[idx];
        S[idx] = h;                              // S becomes h_in
        h = fmaf(pp, h, ss);
    }
}

// ---------------- K5: phase 3 — replay chunk with h_in, emit y[t][c] --------
__global__ __launch_bounds__(256) void k5_phase3(
    const float* __restrict__ delta, const float* __restrict__ u,
    const float* __restrict__ Bm, const float* __restrict__ Cm,
    const float* __restrict__ A_log, const float* __restrict__ Hin,
    float* __restrict__ y)
{
    int blk = blockIdx.x;
    int ch = blk & 127;
    int db = blk >> 7;
    int b = db & 1, d = db >> 1;
    int c = threadIdx.x;
    int start, outer, inner;
    dir_params(d, start, outer, inner);
    int oi = ch >> 1;
    int ibase = (ch & 1) * 32;
    int p0 = start + outer * oi + inner * ibase;
    __shared__ float sBm[CLEN * NN];
    __shared__ float sCm[CLEN * NN];
    for (int i = threadIdx.x; i < CLEN * NN; i += 256) {
        int j = i >> 4, n = i & 15;
        int p = p0 + inner * j;
        sBm[i] = Bm[((size_t)b * LL + p) * NN + n];
        sCm[i] = Cm[((size_t)b * LL + p) * NN + n];
    }
    float A2[NN];
    #pragma unroll
    for (int n = 0; n < NN; ++n)
        A2[n] = -expf(A_log[c * NN + n]) * 1.4426950408889634f;
    float h[NN];
    #pragma unroll
    for (int n = 0; n < NN; ++n)
        h[n] = Hin[(size_t)blk * 4096 + (size_t)c * 16 + n];
    __syncthreads();
    const float* dbase = delta + (size_t)b * LL * CC + c;
    const float* ubase = u     + (size_t)b * LL * CC + c;
    float* ybase = y + ((size_t)db * LL) * CC + c;
    int tbase = ch * CLEN;
    for (int j = 0; j < CLEN; ++j) {
        int p = p0 + inner * j;
        float dl = dbase[(size_t)p * CC];
        float uv = ubase[(size_t)p * CC];
        float yv = 0.f;
        #pragma unroll
        for (int n = 0; n < NN; ++n) {
            float dA = exp2f(A2[n] * dl);
            h[n] = fmaf(dA, h[n], uv * sBm[j * 16 + n]);
            yv = fmaf(h[n], sCm[j * 16 + n], yv);
        }
        ybase[(size_t)(tbase + j) * CC] = 0.25f * yv;
    }
}

// ---------------- K6: gather 4 directions + x*D, transpose to (B,C,L) -------
__global__ __launch_bounds__(256) void k6_reduce(
    const float* __restrict__ feat, const float* __restrict__ D,
    const float* __restrict__ y, float* __restrict__ out)
{
    int pt = blockIdx.x & 63;
    int ct = (blockIdx.x >> 6) & 3;
    int b  = blockIdx.x >> 8;
    int p0 = pt * 64, c0 = ct * 64;
    __shared__ float tile[64 * 65];
    {
        int cl = threadIdx.x & 63;
        int pg = threadIdx.x >> 6;
        #pragma unroll
        for (int pp = 0; pp < 16; ++pp) {
            int pl = pp * 4 + pg;
            int p = p0 + pl;
            int hh = p >> 6, ww = p & 63;
            int t1 = p;
            int t2 = 4095 - p;
            int t3 = (63 - hh) * 64 + ww;
            int t4 = (63 - ww) * 64 + hh;
            int c = c0 + cl;
            float s = y[((size_t)(0 + b) * LL + t1) * CC + c]
                    + y[((size_t)(2 + b) * LL + t2) * CC + c]
                    + y[((size_t)(4 + b) * LL + t3) * CC + c]
                    + y[((size_t)(6 + b) * LL + t4) * CC + c];
            tile[cl * 65 + pl] = s;
        }
    }
    __syncthreads();
    {
        int pl = threadIdx.x & 63;
        int cg = threadIdx.x >> 6;
        #pragma unroll
        for (int cc = 0; cc < 16; ++cc) {
            int cloc = cc * 4 + cg;
            int c = c0 + cloc;
            size_t o = ((size_t)b * CC + c) * LL + p0 + pl;
            out[o] = tile[cloc * 65 + pl] + feat[o] * D[c];
        }
    }
}

extern "C" void kernel_launch(void* const* d_in, const int* in_sizes, int n_in,
                              void* d_out, int out_size, void* d_ws, size_t ws_size,
                              hipStream_t stream)
{
    const float* feat  = (const float*)d_in[0];
    const float* A_log = (const float*)d_in[1];
    const float* D     = (const float*)d_in[2];
    const float* Wd    = (const float*)d_in[3];
    const float* bd    = (const float*)d_in[4];
    const float* WB    = (const float*)d_in[5];
    const float* WC    = (const float*)d_in[6];
    float* out = (float*)d_out;

    float* ws    = (float*)d_ws;
    float* delta = ws;                                   // B*L*C   = 2,097,152
    float* u     = delta + (size_t)BB * LL * CC;         // B*L*C   = 2,097,152
    float* Bm    = u     + (size_t)BB * LL * CC;         // B*L*N   =   131,072
    float* Cm    = Bm    + (size_t)BB * LL * NN;         // B*L*N   =   131,072
    float* P     = Cm    + (size_t)BB * LL * NN;         // 4*B*NCH*C*N = 4,194,304
    float* S     = P     + (size_t)4 * BB * NCH * CC * NN;
    float* y     = S     + (size_t)4 * BB * NCH * CC * NN; // 4*B*L*C = 8,388,608
    // total ws: ~85 MB

    k1_delta_gemm<<<512, 256, 0, stream>>>(feat, Wd, bd, delta, u);
    k2_bc_gemm<<<128, 256, 0, stream>>>(feat, WB, WC, Bm, Cm);
    k3_phase1<<<1024, 256, 0, stream>>>(delta, u, Bm, A_log, P, S);
    k4_phase2<<<128, 256, 0, stream>>>(P, S);
    k5_phase3<<<1024, 256, 0, stream>>>(delta, u, Bm, Cm, A_log, S, y);
    k6_reduce<<<512, 256, 0, stream>>>(feat, D, y, out);
}

// Round 2
// 223.142 us; speedup vs baseline: 1.1624x; 1.1624x over previous
//
#include <hip/hip_runtime.h>
#include <cstdint>
#include <cstddef>

#define BB 2
#define CC 256
#define NN 16
#define LL 4096
#define NCH 128
#define CLEN 32
#define LOG2E 1.4426950408889634f

__device__ __forceinline__ float softplus_f(float z) {
    return fmaxf(z, 0.f) + log1pf(expf(-fabsf(z)));
}

// ---------------- K1: delta = softplus(X @ W_delta + b), du interleaved -----
// X[l,k] = feat[b,k,l]; out du[b][l][c] = (delta, delta*x) float2 pairs.
__global__ __launch_bounds__(256) void k1_delta_gemm(
    const float* __restrict__ feat, const float* __restrict__ Wd,
    const float* __restrict__ bd, float* __restrict__ du)
{
    int ctile = blockIdx.x & 3;
    int lt    = (blockIdx.x >> 2) & 63;
    int b     = blockIdx.x >> 8;
    int l0 = lt * 64, c0 = ctile * 64;
    __shared__ float As[16][64];
    __shared__ float Bs[16][64];
    int tx = threadIdx.x & 15, ty = threadIdx.x >> 4;
    int arow = ty;
    int acol = tx * 4;
    float acc[4][4] = {};
    const float* fbase = feat + (size_t)b * CC * LL;
    for (int k0 = 0; k0 < 256; k0 += 16) {
        __syncthreads();
        *(float4*)&As[arow][acol] = *(const float4*)&fbase[(size_t)(k0 + arow) * LL + l0 + acol];
        *(float4*)&Bs[arow][acol] = *(const float4*)&Wd[(size_t)(k0 + arow) * CC + c0 + acol];
        __syncthreads();
        #pragma unroll
        for (int kk = 0; kk < 16; ++kk) {
            float4 a = *(float4*)&As[kk][ty * 4];
            float4 w = *(float4*)&Bs[kk][tx * 4];
            float av[4] = {a.x, a.y, a.z, a.w};
            float wv[4] = {w.x, w.y, w.z, w.w};
            #pragma unroll
            for (int i = 0; i < 4; ++i)
                #pragma unroll
                for (int j = 0; j < 4; ++j)
                    acc[i][j] = fmaf(av[i], wv[j], acc[i][j]);
        }
    }
    float bdv[4];
    #pragma unroll
    for (int j = 0; j < 4; ++j) bdv[j] = bd[c0 + tx * 4 + j];
    float4 fcol[4];
    #pragma unroll
    for (int j = 0; j < 4; ++j)
        fcol[j] = *(const float4*)&fbase[(size_t)(c0 + tx * 4 + j) * LL + l0 + ty * 4];
    float fc[4][4];
    fc[0][0]=fcol[0].x; fc[0][1]=fcol[1].x; fc[0][2]=fcol[2].x; fc[0][3]=fcol[3].x;
    fc[1][0]=fcol[0].y; fc[1][1]=fcol[1].y; fc[1][2]=fcol[2].y; fc[1][3]=fcol[3].y;
    fc[2][0]=fcol[0].z; fc[2][1]=fcol[1].z; fc[2][2]=fcol[2].z; fc[2][3]=fcol[3].z;
    fc[3][0]=fcol[0].w; fc[3][1]=fcol[1].w; fc[3][2]=fcol[2].w; fc[3][3]=fcol[3].w;
    float4* du4 = (float4*)du;
    #pragma unroll
    for (int i = 0; i < 4; ++i) {
        int l = l0 + ty * 4 + i;
        float dv[4], uv[4];
        #pragma unroll
        for (int j = 0; j < 4; ++j) {
            float z = acc[i][j] + bdv[j];
            dv[j] = softplus_f(z);
            uv[j] = dv[j] * fc[i][j];
        }
        size_t o = (((size_t)b * LL + l) * CC + c0 + tx * 4) >> 1;  // float4 idx
        du4[o]     = make_float4(dv[0], uv[0], dv[1], uv[1]);
        du4[o + 1] = make_float4(dv[2], uv[2], dv[3], uv[3]);
    }
}

// ---------------- K2: Bm = X @ W_B, Cm = X @ W_C (uniform W -> s_loads) -----
__global__ __launch_bounds__(256) void k2_bc_gemm(
    const float* __restrict__ feat, const float* __restrict__ WB,
    const float* __restrict__ WC, float* __restrict__ Bm, float* __restrict__ Cm)
{
    int b = blockIdx.x >> 4;
    int l = (blockIdx.x & 15) * 256 + threadIdx.x;
    float aB[16] = {}, aC[16] = {};
    const float* f = feat + (size_t)b * CC * LL + l;
    #pragma unroll 4
    for (int k = 0; k < 256; ++k) {
        float xv = f[(size_t)k * LL];
        #pragma unroll
        for (int n = 0; n < 16; ++n) {
            aB[n] = fmaf(xv, WB[k * 16 + n], aB[n]);
            aC[n] = fmaf(xv, WC[k * 16 + n], aC[n]);
        }
    }
    size_t o = ((size_t)b * LL + l) * NN;
    #pragma unroll
    for (int q = 0; q < 4; ++q) {
        *(float4*)&Bm[o + q * 4] = make_float4(aB[q*4], aB[q*4+1], aB[q*4+2], aB[q*4+3]);
        *(float4*)&Cm[o + q * 4] = make_float4(aC[q*4], aC[q*4+1], aC[q*4+2], aC[q*4+3]);
    }
}

// ---------------- P1: per-chunk aggregates for 3 order-classes --------------
// cls0: ascending-w half-rows (serves d0 AND d2); cls1: descending (d1);
// cls2: column chunks (d3). grid 768 = cls*256 + b*128 + ch.
__global__ __launch_bounds__(256, 4) void p1_aggr(
    const float2* __restrict__ du, const float* __restrict__ Bm,
    const float* __restrict__ A_log, float* __restrict__ P, float* __restrict__ S)
{
    int blk = blockIdx.x;
    int cls = blk >> 8;
    int b   = (blk >> 7) & 1;
    int ch  = blk & 127;
    int p0, inner;
    if (cls == 0)      { p0 = 32 * ch;        inner = 1; }
    else if (cls == 1) { p0 = 4095 - 32 * ch; inner = -1; }
    else               { p0 = 63 - (ch >> 1) + 2048 * (ch & 1); inner = 64; }
    int c = threadIdx.x;
    __shared__ float sBm[CLEN * NN];
    for (int i = threadIdx.x; i < CLEN * NN; i += 256) {
        int j = i >> 4, n = i & 15;
        sBm[i] = Bm[((size_t)b * LL + (p0 + inner * j)) * NN + n];
    }
    float A2[NN];
    {
        const float4* al = (const float4*)(A_log + c * NN);
        #pragma unroll
        for (int q = 0; q < 4; ++q) {
            float4 v = al[q];
            A2[q*4+0] = -expf(v.x) * LOG2E;
            A2[q*4+1] = -expf(v.y) * LOG2E;
            A2[q*4+2] = -expf(v.z) * LOG2E;
            A2[q*4+3] = -expf(v.w) * LOG2E;
        }
    }
    __syncthreads();
    float Sv[NN] = {};
    float sumd = 0.f;
    const float2* dub = du + (size_t)b * LL * CC + c;
    for (int j = 0; j < CLEN; ++j) {
        float2 dv = dub[(size_t)(p0 + inner * j) * CC];
        sumd += dv.x;
        float dA[NN];
        #pragma unroll
        for (int n = 0; n < NN; ++n) dA[n] = __builtin_amdgcn_exp2f(A2[n] * dv.x);
        #pragma unroll
        for (int n = 0; n < NN; ++n)
            Sv[n] = fmaf(dA[n], Sv[n], dv.y * sBm[j * 16 + n]);
    }
    size_t base = ((size_t)((cls * 2 + b) * 128 + ch)) * 4096 + (size_t)c * 16;
    #pragma unroll
    for (int n = 0; n < NN; ++n) {
        P[base + n] = __builtin_amdgcn_exp2f(A2[n] * sumd);
        S[base + n] = Sv[n];
    }
}

// ---------------- P2: scan chunk aggregates per direction -> Hin ------------
__global__ __launch_bounds__(128) void p2_scan(
    const float* __restrict__ P, const float* __restrict__ S, float* __restrict__ Hin)
{
    int r = blockIdx.x * 128 + threadIdx.x;   // 32768 rows
    int cn = r & 4095;
    int db = r >> 12;
    int d = db >> 1;
    int cls = (d == 1) ? 1 : ((d == 3) ? 2 : 0);
    int b = db & 1;
    const size_t cbase = ((size_t)(cls * 2 + b) * 128) * 4096 + cn;
    const size_t obase = ((size_t)db * 128) * 4096 + cn;
    float h = 0.f;
    for (int g = 0; g < 16; ++g) {
        float pv[8], sv[8];
        #pragma unroll
        for (int i = 0; i < 8; ++i) {
            int ch = g * 8 + i;
            int chm = (d == 2) ? (126 - 2 * (ch >> 1) + (ch & 1)) : ch;
            size_t ix = cbase + (size_t)chm * 4096;
            pv[i] = P[ix];
            sv[i] = S[ix];
        }
        #pragma unroll
        for (int i = 0; i < 8; ++i) {
            Hin[obase + (size_t)(g * 8 + i) * 4096] = h;
            h = fmaf(pv[i], h, sv[i]);
        }
    }
}

// ---------------- P3: replay chunks. sec0: d0+d2 shared sweep; sec1: d1;
// sec2: d3. y buffers indexed by token p (pre-summed for d0+d2). -------------
__global__ __launch_bounds__(256, 4) void p3_replay(
    const float2* __restrict__ du, const float* __restrict__ Bm,
    const float* __restrict__ Cm, const float* __restrict__ A_log,
    const float* __restrict__ Hin, float* __restrict__ yA,
    float* __restrict__ yB, float* __restrict__ yC)
{
    int blk = blockIdx.x;
    int sec = blk >> 8;
    int b   = (blk >> 7) & 1;
    int ch  = blk & 127;
    int p0, inner;
    if (sec == 0)      { p0 = 32 * ch;        inner = 1; }
    else if (sec == 1) { p0 = 4095 - 32 * ch; inner = -1; }
    else               { p0 = 63 - (ch >> 1) + 2048 * (ch & 1); inner = 64; }
    int c = threadIdx.x;
    __shared__ float sBm[CLEN * NN];
    __shared__ float sCm[CLEN * NN];
    for (int i = threadIdx.x; i < CLEN * NN; i += 256) {
        int j = i >> 4, n = i & 15;
        size_t o = ((size_t)b * LL + (p0 + inner * j)) * NN + n;
        sBm[i] = Bm[o];
        sCm[i] = Cm[o];
    }
    float A2[NN];
    {
        const float4* al = (const float4*)(A_log + c * NN);
        #pragma unroll
        for (int q = 0; q < 4; ++q) {
            float4 v = al[q];
            A2[q*4+0] = -expf(v.x) * LOG2E;
            A2[q*4+1] = -expf(v.y) * LOG2E;
            A2[q*4+2] = -expf(v.z) * LOG2E;
            A2[q*4+3] = -expf(v.w) * LOG2E;
        }
    }
    const float2* dub = du + (size_t)b * LL * CC + c;

    if (sec == 0) {
        // shared sweep for d0 (db=0*2+b) and d2 (db=2*2+b)
        int ch2 = 126 - (ch & ~1) + (ch & 1);
        float h0[NN], h2[NN];
        {
            const float4* hp0 = (const float4*)(Hin + ((size_t)(0 * 2 + b) * 128 + ch)  * 4096 + (size_t)c * 16);
            const float4* hp2 = (const float4*)(Hin + ((size_t)(2 * 2 + b) * 128 + ch2) * 4096 + (size_t)c * 16);
            #pragma unroll
            for (int q = 0; q < 4; ++q) {
                float4 v0 = hp0[q], v2 = hp2[q];
                h0[q*4+0]=v0.x; h0[q*4+1]=v0.y; h0[q*4+2]=v0.z; h0[q*4+3]=v0.w;
                h2[q*4+0]=v2.x; h2[q*4+1]=v2.y; h2[q*4+2]=v2.z; h2[q*4+3]=v2.w;
            }
        }
        __syncthreads();
        for (int j = 0; j < CLEN; ++j) {
            int p = p0 + j;
            float2 dv = dub[(size_t)p * CC];
            float dA[NN];
            #pragma unroll
            for (int n = 0; n < NN; ++n) dA[n] = __builtin_amdgcn_exp2f(A2[n] * dv.x);
            float y0v = 0.f, y2v = 0.f;
            #pragma unroll
            for (int n = 0; n < NN; ++n) {
                float Bu = dv.y * sBm[j * 16 + n];
                float cm = sCm[j * 16 + n];
                h0[n] = fmaf(dA[n], h0[n], Bu);
                h2[n] = fmaf(dA[n], h2[n], Bu);
                y0v = fmaf(h0[n], cm, y0v);
                y2v = fmaf(h2[n], cm, y2v);
            }
            yA[((size_t)b * LL + p) * CC + c] = 0.25f * (y0v + y2v);
        }
    } else {
        int d = (sec == 1) ? 1 : 3;
        float h[NN];
        {
            const float4* hp = (const float4*)(Hin + ((size_t)(d * 2 + b) * 128 + ch) * 4096 + (size_t)c * 16);
            #pragma unroll
            for (int q = 0; q < 4; ++q) {
                float4 v = hp[q];
                h[q*4+0]=v.x; h[q*4+1]=v.y; h[q*4+2]=v.z; h[q*4+3]=v.w;
            }
        }
        __syncthreads();
        float* yD = (sec == 1) ? yB : yC;
        for (int j = 0; j < CLEN; ++j) {
            int p = p0 + inner * j;
            float2 dv = dub[(size_t)p * CC];
            float dA[NN];
            #pragma unroll
            for (int n = 0; n < NN; ++n) dA[n] = __builtin_amdgcn_exp2f(A2[n] * dv.x);
            float yv = 0.f;
            #pragma unroll
            for (int n = 0; n < NN; ++n) {
                float Bu = dv.y * sBm[j * 16 + n];
                h[n] = fmaf(dA[n], h[n], Bu);
                yv = fmaf(h[n], sCm[j * 16 + n], yv);
            }
            yD[((size_t)b * LL + p) * CC + c] = 0.25f * yv;
        }
    }
}

// ---------------- K6: sum 3 y-buffers + x*D, transpose to (B,C,L) -----------
__global__ __launch_bounds__(256) void k6_reduce(
    const float* __restrict__ feat, const float* __restrict__ D,
    const float* __restrict__ yA, const float* __restrict__ yB,
    const float* __restrict__ yC, float* __restrict__ out)
{
    int pt = blockIdx.x & 63;
    int ct = (blockIdx.x >> 6) & 3;
    int b  = blockIdx.x >> 8;
    int p0 = pt * 64, c0 = ct * 64;
    __shared__ float tile[64 * 65];
    {
        int cl = threadIdx.x & 63;
        int pg = threadIdx.x >> 6;
        #pragma unroll
        for (int pp = 0; pp < 16; ++pp) {
            int pl = pp * 4 + pg;
            size_t ix = ((size_t)b * LL + p0 + pl) * CC + c0 + cl;
            tile[cl * 65 + pl] = yA[ix] + yB[ix] + yC[ix];
        }
    }
    __syncthreads();
    {
        int pl = threadIdx.x & 63;
        int cg = threadIdx.x >> 6;
        #pragma unroll
        for (int cc = 0; cc < 16; ++cc) {
            int cloc = cc * 4 + cg;
            int c = c0 + cloc;
            size_t o = ((size_t)b * CC + c) * LL + p0 + pl;
            out[o] = tile[cloc * 65 + pl] + feat[o] * D[c];
        }
    }
}

extern "C" void kernel_launch(void* const* d_in, const int* in_sizes, int n_in,
                              void* d_out, int out_size, void* d_ws, size_t ws_size,
                              hipStream_t stream)
{
    const float* feat  = (const float*)d_in[0];
    const float* A_log = (const float*)d_in[1];
    const float* D     = (const float*)d_in[2];
    const float* Wd    = (const float*)d_in[3];
    const float* bd    = (const float*)d_in[4];
    const float* WB    = (const float*)d_in[5];
    const float* WC    = (const float*)d_in[6];
    float* out = (float*)d_out;

    float* ws  = (float*)d_ws;
    float* du  = ws;                                      //  4,194,304 (float2 pairs)
    float* Bm  = du  + (size_t)4194304;                   //    131,072
    float* Cm  = Bm  + (size_t)131072;                    //    131,072
    float* P   = Cm  + (size_t)131072;                    //  3,145,728 (3 cls)
    float* S   = P   + (size_t)3145728;                   //  3,145,728
    float* Hin = S   + (size_t)3145728;                   //  4,194,304 (4 dirs)
    float* yA  = Hin + (size_t)4194304;                   //  2,097,152
    float* yB  = yA  + (size_t)2097152;                   //  2,097,152
    float* yC  = yB  + (size_t)2097152;                   //  2,097,152
    // total 21,233,664 floats = 84.9 MB

    k1_delta_gemm<<<512, 256, 0, stream>>>(feat, Wd, bd, du);
    k2_bc_gemm<<<32, 256, 0, stream>>>(feat, WB, WC, Bm, Cm);
    p1_aggr<<<768, 256, 0, stream>>>((const float2*)du, Bm, A_log, P, S);
    p2_scan<<<256, 128, 0, stream>>>(P, S, Hin);
    p3_replay<<<768, 256, 0, stream>>>((const float2*)du, Bm, Cm, A_log, Hin, yA, yB, yC);
    k6_reduce<<<512, 256, 0, stream>>>(feat, D, yA, yB, yC, out);
}

// Round 3
// 176.585 us; speedup vs baseline: 1.4689x; 1.2637x over previous
//
#include <hip/hip_runtime.h>
#include <cstdint>
#include <cstddef>

#define BB 2
#define CC 256
#define NN 16
#define LL 4096
#define NCH 128
#define CLEN 32
#define LOG2E 1.4426950408889634f

__device__ __forceinline__ float softplus_f(float z) {
    return fmaxf(z, 0.f) + log1pf(expf(-fabsf(z)));
}

// ---------------- K1: delta = softplus(X @ W_delta + b), du interleaved -----
// X[l,k] = feat[b,k,l]; out du[b][l][c] = (delta, delta*x) float2 pairs.
// ctile==0 blocks ALSO compute Bm = X@W_B, Cm = X@W_C from the same As tiles
// (k2 of round 2 was 62 us at 1.3% occupancy -- fused here for free).
__global__ __launch_bounds__(256) void k1_delta_gemm(
    const float* __restrict__ feat, const float* __restrict__ Wd,
    const float* __restrict__ bd, const float* __restrict__ WB,
    const float* __restrict__ WC, float* __restrict__ du,
    float* __restrict__ Bm, float* __restrict__ Cm)
{
    int ctile = blockIdx.x & 3;
    int lt    = (blockIdx.x >> 2) & 63;
    int b     = blockIdx.x >> 8;
    int l0 = lt * 64, c0 = ctile * 64;
    __shared__ float As[16][64];
    __shared__ float Bs[16][64];
    __shared__ float sW[8192];          // WB (4096) then WC (4096)
    int tx = threadIdx.x & 15, ty = threadIdx.x >> 4;
    int arow = ty;
    int acol = tx * 4;
    float acc[4][4] = {};
    const bool doBC = (ctile == 0);     // block-uniform
    // BC mapping: lane l within tile + quarter-group selecting output slice
    int lloc = threadIdx.x & 63;
    int half = threadIdx.x >> 6;        // 0,1 -> Bm n[0:8),[8:16); 2,3 -> Cm
    int nb   = (half & 1) * 8;
    float accBC[8] = {};
    if (doBC) {
        for (int i = threadIdx.x; i < 4096; i += 256) {
            sW[i]        = WB[i];
            sW[4096 + i] = WC[i];
        }
    }
    const float* fbase = feat + (size_t)b * CC * LL;
    for (int k0 = 0; k0 < 256; k0 += 16) {
        __syncthreads();
        *(float4*)&As[arow][acol] = *(const float4*)&fbase[(size_t)(k0 + arow) * LL + l0 + acol];
        *(float4*)&Bs[arow][acol] = *(const float4*)&Wd[(size_t)(k0 + arow) * CC + c0 + acol];
        __syncthreads();
        #pragma unroll
        for (int kk = 0; kk < 16; ++kk) {
            float4 a = *(float4*)&As[kk][ty * 4];
            float4 w = *(float4*)&Bs[kk][tx * 4];
            float av[4] = {a.x, a.y, a.z, a.w};
            float wv[4] = {w.x, w.y, w.z, w.w};
            #pragma unroll
            for (int i = 0; i < 4; ++i)
                #pragma unroll
                for (int j = 0; j < 4; ++j)
                    acc[i][j] = fmaf(av[i], wv[j], acc[i][j]);
        }
        if (doBC) {
            const float* wbase = &sW[(half >> 1) * 4096 + nb];
            #pragma unroll
            for (int kk = 0; kk < 16; ++kk) {
                float xv = As[kk][lloc];
                float4 w0 = *(const float4*)&wbase[(k0 + kk) * 16];
                float4 w1 = *(const float4*)&wbase[(k0 + kk) * 16 + 4];
                accBC[0] = fmaf(xv, w0.x, accBC[0]);
                accBC[1] = fmaf(xv, w0.y, accBC[1]);
                accBC[2] = fmaf(xv, w0.z, accBC[2]);
                accBC[3] = fmaf(xv, w0.w, accBC[3]);
                accBC[4] = fmaf(xv, w1.x, accBC[4]);
                accBC[5] = fmaf(xv, w1.y, accBC[5]);
                accBC[6] = fmaf(xv, w1.z, accBC[6]);
                accBC[7] = fmaf(xv, w1.w, accBC[7]);
            }
        }
    }
    if (doBC) {
        float* dst = ((half >> 1) ? Cm : Bm) + ((size_t)b * LL + l0 + lloc) * NN + nb;
        *(float4*)&dst[0] = make_float4(accBC[0], accBC[1], accBC[2], accBC[3]);
        *(float4*)&dst[4] = make_float4(accBC[4], accBC[5], accBC[6], accBC[7]);
    }
    float bdv[4];
    #pragma unroll
    for (int j = 0; j < 4; ++j) bdv[j] = bd[c0 + tx * 4 + j];
    float4 fcol[4];
    #pragma unroll
    for (int j = 0; j < 4; ++j)
        fcol[j] = *(const float4*)&fbase[(size_t)(c0 + tx * 4 + j) * LL + l0 + ty * 4];
    float fc[4][4];
    fc[0][0]=fcol[0].x; fc[0][1]=fcol[1].x; fc[0][2]=fcol[2].x; fc[0][3]=fcol[3].x;
    fc[1][0]=fcol[0].y; fc[1][1]=fcol[1].y; fc[1][2]=fcol[2].y; fc[1][3]=fcol[3].y;
    fc[2][0]=fcol[0].z; fc[2][1]=fcol[1].z; fc[2][2]=fcol[2].z; fc[2][3]=fcol[3].z;
    fc[3][0]=fcol[0].w; fc[3][1]=fcol[1].w; fc[3][2]=fcol[2].w; fc[3][3]=fcol[3].w;
    float4* du4 = (float4*)du;
    #pragma unroll
    for (int i = 0; i < 4; ++i) {
        int l = l0 + ty * 4 + i;
        float dv[4], uv[4];
        #pragma unroll
        for (int j = 0; j < 4; ++j) {
            float z = acc[i][j] + bdv[j];
            dv[j] = softplus_f(z);
            uv[j] = dv[j] * fc[i][j];
        }
        size_t o = (((size_t)b * LL + l) * CC + c0 + tx * 4) >> 1;  // float4 idx
        du4[o]     = make_float4(dv[0], uv[0], dv[1], uv[1]);
        du4[o + 1] = make_float4(dv[2], uv[2], dv[3], uv[3]);
    }
}

// ---------------- P1: per-chunk aggregates for 3 order-classes --------------
// cls0: ascending-w half-rows (serves d0 AND d2); cls1: descending (d1);
// cls2: column chunks (d3). grid 768 = cls*256 + b*128 + ch.
__global__ __launch_bounds__(256, 4) void p1_aggr(
    const float2* __restrict__ du, const float* __restrict__ Bm,
    const float* __restrict__ A_log, float* __restrict__ P, float* __restrict__ S)
{
    int blk = blockIdx.x;
    int cls = blk >> 8;
    int b   = (blk >> 7) & 1;
    int ch  = blk & 127;
    int p0, inner;
    if (cls == 0)      { p0 = 32 * ch;        inner = 1; }
    else if (cls == 1) { p0 = 4095 - 32 * ch; inner = -1; }
    else               { p0 = 63 - (ch >> 1) + 2048 * (ch & 1); inner = 64; }
    int c = threadIdx.x;
    __shared__ float sBm[CLEN * NN];
    for (int i = threadIdx.x; i < CLEN * NN; i += 256) {
        int j = i >> 4, n = i & 15;
        sBm[i] = Bm[((size_t)b * LL + (p0 + inner * j)) * NN + n];
    }
    float A2[NN];
    {
        const float4* al = (const float4*)(A_log + c * NN);
        #pragma unroll
        for (int q = 0; q < 4; ++q) {
            float4 v = al[q];
            A2[q*4+0] = -expf(v.x) * LOG2E;
            A2[q*4+1] = -expf(v.y) * LOG2E;
            A2[q*4+2] = -expf(v.z) * LOG2E;
            A2[q*4+3] = -expf(v.w) * LOG2E;
        }
    }
    __syncthreads();
    float Sv[NN] = {};
    float sumd = 0.f;
    const float2* dub = du + (size_t)b * LL * CC + c;
    for (int j = 0; j < CLEN; ++j) {
        float2 dv = dub[(size_t)(p0 + inner * j) * CC];
        sumd += dv.x;
        float dA[NN];
        #pragma unroll
        for (int n = 0; n < NN; ++n) dA[n] = __builtin_amdgcn_exp2f(A2[n] * dv.x);
        #pragma unroll
        for (int n = 0; n < NN; ++n)
            Sv[n] = fmaf(dA[n], Sv[n], dv.y * sBm[j * 16 + n]);
    }
    size_t base = ((size_t)((cls * 2 + b) * 128 + ch)) * 4096 + (size_t)c * 16;
    #pragma unroll
    for (int n = 0; n < NN; ++n) {
        P[base + n] = __builtin_amdgcn_exp2f(A2[n] * sumd);
        S[base + n] = Sv[n];
    }
}

// ---------------- P2: scan chunk aggregates per direction -> Hin ------------
__global__ __launch_bounds__(128) void p2_scan(
    const float* __restrict__ P, const float* __restrict__ S, float* __restrict__ Hin)
{
    int r = blockIdx.x * 128 + threadIdx.x;   // 32768 rows
    int cn = r & 4095;
    int db = r >> 12;
    int d = db >> 1;
    int cls = (d == 1) ? 1 : ((d == 3) ? 2 : 0);
    int b = db & 1;
    const size_t cbase = ((size_t)(cls * 2 + b) * 128) * 4096 + cn;
    const size_t obase = ((size_t)db * 128) * 4096 + cn;
    float h = 0.f;
    for (int g = 0; g < 16; ++g) {
        float pv[8], sv[8];
        #pragma unroll
        for (int i = 0; i < 8; ++i) {
            int ch = g * 8 + i;
            int chm = (d == 2) ? (126 - 2 * (ch >> 1) + (ch & 1)) : ch;
            size_t ix = cbase + (size_t)chm * 4096;
            pv[i] = P[ix];
            sv[i] = S[ix];
        }
        #pragma unroll
        for (int i = 0; i < 8; ++i) {
            Hin[obase + (size_t)(g * 8 + i) * 4096] = h;
            h = fmaf(pv[i], h, sv[i]);
        }
    }
}

// ---------------- P3: replay chunks. sec0: d0+d2 shared sweep; sec1: d1;
// sec2: d3. y buffers indexed by token p (pre-summed for d0+d2). -------------
__global__ __launch_bounds__(256, 4) void p3_replay(
    const float2* __restrict__ du, const float* __restrict__ Bm,
    const float* __restrict__ Cm, const float* __restrict__ A_log,
    const float* __restrict__ Hin, float* __restrict__ yA,
    float* __restrict__ yB, float* __restrict__ yC)
{
    int blk = blockIdx.x;
    int sec = blk >> 8;
    int b   = (blk >> 7) & 1;
    int ch  = blk & 127;
    int p0, inner;
    if (sec == 0)      { p0 = 32 * ch;        inner = 1; }
    else if (sec == 1) { p0 = 4095 - 32 * ch; inner = -1; }
    else               { p0 = 63 - (ch >> 1) + 2048 * (ch & 1); inner = 64; }
    int c = threadIdx.x;
    __shared__ float sBm[CLEN * NN];
    __shared__ float sCm[CLEN * NN];
    for (int i = threadIdx.x; i < CLEN * NN; i += 256) {
        int j = i >> 4, n = i & 15;
        size_t o = ((size_t)b * LL + (p0 + inner * j)) * NN + n;
        sBm[i] = Bm[o];
        sCm[i] = Cm[o];
    }
    float A2[NN];
    {
        const float4* al = (const float4*)(A_log + c * NN);
        #pragma unroll
        for (int q = 0; q < 4; ++q) {
            float4 v = al[q];
            A2[q*4+0] = -expf(v.x) * LOG2E;
            A2[q*4+1] = -expf(v.y) * LOG2E;
            A2[q*4+2] = -expf(v.z) * LOG2E;
            A2[q*4+3] = -expf(v.w) * LOG2E;
        }
    }
    const float2* dub = du + (size_t)b * LL * CC + c;

    if (sec == 0) {
        // shared sweep for d0 (db=0*2+b) and d2 (db=2*2+b)
        int ch2 = 126 - (ch & ~1) + (ch & 1);
        float h0[NN], h2[NN];
        {
            const float4* hp0 = (const float4*)(Hin + ((size_t)(0 * 2 + b) * 128 + ch)  * 4096 + (size_t)c * 16);
            const float4* hp2 = (const float4*)(Hin + ((size_t)(2 * 2 + b) * 128 + ch2) * 4096 + (size_t)c * 16);
            #pragma unroll
            for (int q = 0; q < 4; ++q) {
                float4 v0 = hp0[q], v2 = hp2[q];
                h0[q*4+0]=v0.x; h0[q*4+1]=v0.y; h0[q*4+2]=v0.z; h0[q*4+3]=v0.w;
                h2[q*4+0]=v2.x; h2[q*4+1]=v2.y; h2[q*4+2]=v2.z; h2[q*4+3]=v2.w;
            }
        }
        __syncthreads();
        for (int j = 0; j < CLEN; ++j) {
            int p = p0 + j;
            float2 dv = dub[(size_t)p * CC];
            float dA[NN];
            #pragma unroll
            for (int n = 0; n < NN; ++n) dA[n] = __builtin_amdgcn_exp2f(A2[n] * dv.x);
            float y0v = 0.f, y2v = 0.f;
            #pragma unroll
            for (int n = 0; n < NN; ++n) {
                float Bu = dv.y * sBm[j * 16 + n];
                float cm = sCm[j * 16 + n];
                h0[n] = fmaf(dA[n], h0[n], Bu);
                h2[n] = fmaf(dA[n], h2[n], Bu);
                y0v = fmaf(h0[n], cm, y0v);
                y2v = fmaf(h2[n], cm, y2v);
            }
            yA[((size_t)b * LL + p) * CC + c] = 0.25f * (y0v + y2v);
        }
    } else {
        int d = (sec == 1) ? 1 : 3;
        float h[NN];
        {
            const float4* hp = (const float4*)(Hin + ((size_t)(d * 2 + b) * 128 + ch) * 4096 + (size_t)c * 16);
            #pragma unroll
            for (int q = 0; q < 4; ++q) {
                float4 v = hp[q];
                h[q*4+0]=v.x; h[q*4+1]=v.y; h[q*4+2]=v.z; h[q*4+3]=v.w;
            }
        }
        __syncthreads();
        float* yD = (sec == 1) ? yB : yC;
        for (int j = 0; j < CLEN; ++j) {
            int p = p0 + inner * j;
            float2 dv = dub[(size_t)p * CC];
            float dA[NN];
            #pragma unroll
            for (int n = 0; n < NN; ++n) dA[n] = __builtin_amdgcn_exp2f(A2[n] * dv.x);
            float yv = 0.f;
            #pragma unroll
            for (int n = 0; n < NN; ++n) {
                float Bu = dv.y * sBm[j * 16 + n];
                h[n] = fmaf(dA[n], h[n], Bu);
                yv = fmaf(h[n], sCm[j * 16 + n], yv);
            }
            yD[((size_t)b * LL + p) * CC + c] = 0.25f * yv;
        }
    }
}

// ---------------- K6: sum 3 y-buffers + x*D, transpose to (B,C,L) -----------
__global__ __launch_bounds__(256) void k6_reduce(
    const float* __restrict__ feat, const float* __restrict__ D,
    const float* __restrict__ yA, const float* __restrict__ yB,
    const float* __restrict__ yC, float* __restrict__ out)
{
    int pt = blockIdx.x & 63;
    int ct = (blockIdx.x >> 6) & 3;
    int b  = blockIdx.x >> 8;
    int p0 = pt * 64, c0 = ct * 64;
    __shared__ float tile[64 * 65];
    {
        int cl = threadIdx.x & 63;
        int pg = threadIdx.x >> 6;
        #pragma unroll
        for (int pp = 0; pp < 16; ++pp) {
            int pl = pp * 4 + pg;
            size_t ix = ((size_t)b * LL + p0 + pl) * CC + c0 + cl;
            tile[cl * 65 + pl] = yA[ix] + yB[ix] + yC[ix];
        }
    }
    __syncthreads();
    {
        int pl = threadIdx.x & 63;
        int cg = threadIdx.x >> 6;
        #pragma unroll
        for (int cc = 0; cc < 16; ++cc) {
            int cloc = cc * 4 + cg;
            int c = c0 + cloc;
            size_t o = ((size_t)b * CC + c) * LL + p0 + pl;
            out[o] = tile[cloc * 65 + pl] + feat[o] * D[c];
        }
    }
}

extern "C" void kernel_launch(void* const* d_in, const int* in_sizes, int n_in,
                              void* d_out, int out_size, void* d_ws, size_t ws_size,
                              hipStream_t stream)
{
    const float* feat  = (const float*)d_in[0];
    const float* A_log = (const float*)d_in[1];
    const float* D     = (const float*)d_in[2];
    const float* Wd    = (const float*)d_in[3];
    const float* bd    = (const float*)d_in[4];
    const float* WB    = (const float*)d_in[5];
    const float* WC    = (const float*)d_in[6];
    float* out = (float*)d_out;

    float* ws  = (float*)d_ws;
    float* du  = ws;                                      //  4,194,304 (float2 pairs)
    float* Bm  = du  + (size_t)4194304;                   //    131,072
    float* Cm  = Bm  + (size_t)131072;                    //    131,072
    float* P   = Cm  + (size_t)131072;                    //  3,145,728 (3 cls)
    float* S   = P   + (size_t)3145728;                   //  3,145,728
    float* Hin = S   + (size_t)3145728;                   //  4,194,304 (4 dirs)
    float* yA  = Hin + (size_t)4194304;                   //  2,097,152
    float* yB  = yA  + (size_t)2097152;                   //  2,097,152
    float* yC  = yB  + (size_t)2097152;                   //  2,097,152
    // total 21,233,664 floats = 84.9 MB

    k1_delta_gemm<<<512, 256, 0, stream>>>(feat, Wd, bd, WB, WC, du, Bm, Cm);
    p1_aggr<<<768, 256, 0, stream>>>((const float2*)du, Bm, A_log, P, S);
    p2_scan<<<256, 128, 0, stream>>>(P, S, Hin);
    p3_replay<<<768, 256, 0, stream>>>((const float2*)du, Bm, Cm, A_log, Hin, yA, yB, yC);
    k6_reduce<<<512, 256, 0, stream>>>(feat, D, yA, yB, yC, out);
}